// Round 4
// baseline (351.525 us; speedup 1.0000x reference)
//
#include <hip/hip_runtime.h>

// LSTM: B=8192, T=512, H=32. Block = 512 threads = TWO independent 16-batch
// groups (A: waves 0-3, B: waves 4-7); grid 256 -> 1 block/CU, 8 waves/CU
// (2/SIMD; SIMD s hosts A-wave s + B-wave s+4).
// SKEWED PHASES: step split into P1 (ds_read h, 2x2 MFMA, 8 exp2 — latency
// chain ~200cy) and P2 (cell algebra: 4 rcp + 2 exp2 + pk-VALU + pack/write —
// issue-dense). Segments: even = A:P1(t) || B:P2(t-1); odd = A:P2(t) || B:P1(t).
// Each SIMD always pairs one chain-bound wave with one issue-dense wave ->
// deterministic anti-phase (R0's 52% duty came from random 2-block drift).
// Each group's h write->read straddles a barrier: race-free. 2 barriers/step.
// Per-wave math = R0 baseline verbatim (absmax 2^-10):
//   Transposed MFMA D = W'*h, mfma_f32_16x16x32_f16, wave w owns tiles 2w,2w+1
//   -> 2 cells/lane (units 8q+2w+tt, batch c). FP16 2-term h (hi+lo planes,
//   2 chained MFMAs). K-perm pi_q(j)=j XOR 2q keeps plane writes 2-way banked.
//   Gates pre-scaled by -log2e (i,f,o) / +2log2e (g): 10 exp2 + 4 rcp per wave.
// Issue model (fit R0-R3): trans = 16cy/wave64 issue-blocking; per-SIMD/step
// issue = P1+P2 for 2 waves ~ 630cy -> predict ~700-800cy wall vs R0's 977.

#define TT 512
#define HH 32
#define L2E 1.44269504088896340736f
#define XROW 132   // x tile row stride (floats): bank (4c+t) mod 32 -> 2-way

typedef _Float16 f16x8 __attribute__((ext_vector_type(8)));
typedef __fp16 fp16x2 __attribute__((ext_vector_type(2)));
typedef float f32x4 __attribute__((ext_vector_type(4)));
typedef float f32x2 __attribute__((ext_vector_type(2)));

__device__ __forceinline__ float fastrcp(float x) { return __builtin_amdgcn_rcpf(x); }
__device__ __forceinline__ float exp2f_(float x) { return __builtin_amdgcn_exp2f(x); }

__launch_bounds__(512, 2)
__global__ void lstm_kernel(const float* __restrict__ x,
                            const float* __restrict__ W_ih,
                            const float* __restrict__ W_hh,
                            const float* __restrict__ b_ih,
                            const float* __restrict__ b_hh,
                            const float* __restrict__ W_fc,
                            const float* __restrict__ b_fc,
                            float* __restrict__ out) {
    // h planes per group: [parity][qblk(4)][batch(16)][j(8)] fp16 = 512/parity
    __shared__ _Float16 hhp[2][2][512];   // [grp][parity][...] h hi
    __shared__ _Float16 hlp[2][2][512];   // h lo
    __shared__ float xbuf[2][16 * XROW];  // [grp] x chunk: 16 batches x 128 t

    const int tid  = threadIdx.x;
    const int lane = tid & 63;
    const int wv   = tid >> 6;        // 0..7
    const int grp  = wv >> 2;         // 0 = A, 1 = B
    const int w    = wv & 3;          // wave-in-group: owns tiles 2w, 2w+1
    const int c    = lane & 15;       // batch (MFMA n); also A m-row
    const int q    = lane >> 4;       // quad: k-block 8q; unit-block 8q
    const int tg   = tid & 255;       // thread-in-group
    const int gbase = blockIdx.x * 32 + grp * 16;

    // ---- A-fragments (weights) for tiles 2w+tt, single fp16, k-perm j^2q ----
    const int gate = c & 3;
    const float asc = (gate == 2) ? (2.0f * L2E) : (-L2E);
    const int wrow0 = gate * 32 + 8 * (c >> 2);
    f16x8 wah[2];
    #pragma unroll
    for (int tt = 0; tt < 2; ++tt) {
        const int t8 = 2 * w + tt;
        #pragma unroll
        for (int j = 0; j < 8; ++j) {
            const int u = 8 * q + (j ^ (2 * q));
            wah[tt][j] = (_Float16)(W_hh[(wrow0 + t8) * HH + u] * asc);
        }
    }

    // ---- per-cell consts: cell tt = (unit 8q + 2w + tt, batch c) ----
    f32x4 wihs[2], bcs[2];
    #pragma unroll
    for (int tt = 0; tt < 2; ++tt) {
        const int u = 8 * q + 2 * w + tt;
        #pragma unroll
        for (int r = 0; r < 4; ++r) {
            const float sc = (r == 2) ? (2.0f * L2E) : (-L2E);
            wihs[tt][r] = W_ih[32 * r + u] * sc;
            bcs[tt][r]  = (b_ih[32 * r + u] + b_hh[32 * r + u]) * sc;
        }
    }

    // ---- init own group's parity-0 planes to zero (h0 = 0) ----
    #pragma unroll
    for (int i = tg; i < 512; i += 256) {
        hhp[grp][0][i] = (_Float16)0.f;
        hlp[grp][0][i] = (_Float16)0.f;
    }

    // ---- stage x chunk 0: 16 rows x 128 floats, 2 float4/thread ----
    const int xrow = tg >> 4;
    const int xj4  = (tg & 15) * 4;
    #pragma unroll
    for (int s = 0; s < 2; ++s) {
        const float4 v = *(const float4*)&x[(size_t)(gbase + xrow) * TT + xj4 + 64 * s];
        *(float4*)&xbuf[grp][xrow * XROW + xj4 + 64 * s] = v;
    }
    __syncthreads();

    // B-frag read offset (fp16 units); h write offset with k-perm (even slot)
    const int rdo = q * 128 + c * 8;
    const int wro = rdo + ((2 * w) ^ (2 * q));

    // ---- carried per-wave state ----
    f32x2 cs2 = {0.f, 0.f};                 // c-state, cells tt=0,1
    f32x2 Ei, Ef, G, Eo;                    // P1 -> P2 carry
    f32x4 ai[2];                            // a-init for next P1
    {
        const float xc = xbuf[grp][c * XROW];
        ai[0] = wihs[0] * xc + bcs[0];
        ai[1] = wihs[1] * xc + bcs[1];
    }

    // P1(t): read h(t) planes, 4 MFMA, 8 exp2 -> Ei,Ef,G,Eo
    auto P1 = [&](int t) {
        const int RP = t & 1;
        const f16x8 bh = *(const f16x8*)&hhp[grp][RP][rdo];
        const f16x8 bl = *(const f16x8*)&hlp[grp][RP][rdo];
        __builtin_amdgcn_s_setprio(1);
        f32x4 a0 = __builtin_amdgcn_mfma_f32_16x16x32_f16(wah[0], bh, ai[0], 0, 0, 0);
        f32x4 a1 = __builtin_amdgcn_mfma_f32_16x16x32_f16(wah[1], bh, ai[1], 0, 0, 0);
        a0 = __builtin_amdgcn_mfma_f32_16x16x32_f16(wah[0], bl, a0, 0, 0, 0);
        a1 = __builtin_amdgcn_mfma_f32_16x16x32_f16(wah[1], bl, a1, 0, 0, 0);
        Ei.x = exp2f_(a0[0]); Ei.y = exp2f_(a1[0]);
        Ef.x = exp2f_(a0[1]); Ef.y = exp2f_(a1[1]);
        G.x  = exp2f_(a0[2]); G.y  = exp2f_(a1[2]);
        Eo.x = exp2f_(a0[3]); Eo.y = exp2f_(a1[3]);
        __builtin_amdgcn_s_setprio(0);
    };

    // P2(t): cell algebra, pack h(t+1), write planes; prefetch ai for t+1
    auto P2 = [&](int t) {
        const int WP = (t & 1) ^ 1;
        const f32x2 one = {1.f, 1.f};
        const f32x2 aig = (one + Ei) * (G + one);
        const f32x2 af  = one + Ef;
        const f32x2 num = cs2 * aig + (G - one) * af;
        const f32x2 den = af * aig;
        f32x2 rc; rc.x = fastrcp(den.x); rc.y = fastrcp(den.y);
        const f32x2 cn = num * rc;
        cs2 = cn;
        f32x2 yc = cn * (2.0f * L2E);
        yc.x = __builtin_amdgcn_fmed3f(yc.x, -60.f, 60.f);
        yc.y = __builtin_amdgcn_fmed3f(yc.y, -60.f, 60.f);
        f32x2 C; C.x = exp2f_(yc.x); C.y = exp2f_(yc.y);
        const f32x2 hden = (C + one) * (one + Eo);
        f32x2 hr; hr.x = fastrcp(hden.x); hr.y = fastrcp(hden.y);
        const f32x2 hv = (C - one) * hr;
        union PK { fp16x2 v; int i; _Float16 e[2]; } ph, pl;
        ph.v = __builtin_amdgcn_cvt_pkrtz(hv.x, hv.y);
        pl.v = __builtin_amdgcn_cvt_pkrtz(hv.x - (float)ph.e[0],
                                          hv.y - (float)ph.e[1]);
        *(int*)&hhp[grp][WP][wro] = ph.i;
        *(int*)&hlp[grp][WP][wro] = pl.i;
        // next step's a-init (x chunk for t+1 staged >= 1 barrier earlier)
        const float xn = xbuf[grp][c * XROW + ((t + 1) & 127)];
        ai[0] = wihs[0] * xn + bcs[0];
        ai[1] = wihs[1] * xn + bcs[1];
    };

    auto stage = [&](int tc) {   // stage x chunk starting at timestep tc
        #pragma unroll
        for (int s = 0; s < 2; ++s) {
            const float4 v = *(const float4*)&x[(size_t)(gbase + xrow) * TT + tc + xj4 + 64 * s];
            *(float4*)&xbuf[grp][xrow * XROW + xj4 + 64 * s] = v;
        }
    };

    #pragma unroll 1
    for (int t = 0; t < TT; ++t) {
        // EVEN segment: A:P1(t) || B:P2(t-1) [+ A stages next x chunk]
        if (grp == 0) {
            P1(t);
            if (((t + 1) & 127) == 0 && (t + 1) < TT) stage(t + 1);
        } else {
            if (t) P2(t - 1);
        }
        __syncthreads();
        // ODD segment: A:P2(t) || B:P1(t) [+ B stages next x chunk]
        if (grp == 0) {
            P2(t);
        } else {
            P1(t);
            if (((t + 1) & 127) == 0 && (t + 1) < TT) stage(t + 1);
        }
        __syncthreads();
    }
    if (grp == 1) P2(TT - 1);   // B finishes its last half-step
    __syncthreads();
    // Both groups' final h(512) in their parity-0 planes.

    // ---- head: out[b] = h_T @ W_fc^T + b_fc (k-perm aware), per group ----
    if (tg < 16) {
        float s = b_fc[0];
        #pragma unroll
        for (int u = 0; u < 32; ++u) {
            const int qb = u >> 3;
            const int off = qb * 128 + tg * 8 + ((u & 7) ^ (2 * qb));
            s += ((float)hhp[grp][0][off] + (float)hlp[grp][0][off]) * W_fc[u];
        }
        out[gbase + tg] = s;
    }
}

extern "C" void kernel_launch(void* const* d_in, const int* in_sizes, int n_in,
                              void* d_out, int out_size, void* d_ws, size_t ws_size,
                              hipStream_t stream) {
    const float* x    = (const float*)d_in[0];
    const float* W_ih = (const float*)d_in[1];
    const float* W_hh = (const float*)d_in[2];
    const float* b_ih = (const float*)d_in[3];
    const float* b_hh = (const float*)d_in[4];
    const float* W_fc = (const float*)d_in[5];
    const float* b_fc = (const float*)d_in[6];
    float* out = (float*)d_out;

    const int B = 8192;
    lstm_kernel<<<B / 32, 512, 0, stream>>>(x, W_ih, W_hh, b_ih, b_hh,
                                            W_fc, b_fc, out);
}